// Round 8
// baseline (249.603 us; speedup 1.0000x reference)
//
#include <hip/hip_runtime.h>
#include <math.h>

// Problem constants (from reference): B=8, S=128, V=32000, K=32.
constexpr int Bc = 8, Sc = 128, Vc = 32000, Kc = 32;
constexpr int NROWS = Bc * Sc;             // 1024
constexpr int V4 = Vc / 4;                 // 8000 float4 per row
constexpr int NT = 1024;                   // 16 waves per block
constexpr int IT = (V4 + NT - 1) / NT;     // 8 float4 per thread per row
constexpr int NW = NT / 64;                // 16
constexpr int RPB = 4;                     // rows per block
constexpr int GRID = NROWS / RPB;          // 256 blocks = 1 per CU

typedef float vfloat4 __attribute__((ext_vector_type(4)));

// Round-8: asm-forced register-resident pipeline.
// R6/R7 post-mortem: hipcc's scheduler refuses dual live buffers (VGPR 56
// both rounds) and its waitcnt pass drains vmcnt before redefining any
// in-flight store-source register -> R/W phases re-serialize regardless of
// source order. Fix (HK T3/T4 discipline, plain HIP + inline asm):
//  * next-row loads are asm-volatile global_load_dwordx4 into a DEDICATED
//    register set n[8] that is never a store source (no protective drain).
//    Volatile-asm ordering pins them before the lgkm-only barrier.
//  * stores are pinned between volatile asms; then a COUNTED s_waitcnt
//    vmcnt(8) (7 for the 7-store tail waves) waits for the loads only --
//    this stage's stores keep flying. Never vmcnt(0) in the loop.
//  * empty "+v" pin-asms after the wait make the exp consume post-wait
//    values (rule-18 fence at both IR and MIR level).
//  * exp writes into the A/B buffer whose previous stores are already
//    retired by our own counted wait.
// Queue per wave per stage: [<=8 prev stores][8 loads][<=8 stores]; in-order
// retire => vmcnt(8) retires prev stores + all loads. Waves 0-12 do 8
// stores (t<832 covers i=7), waves 13-15 do 7 -> wave-uniform vmcnt(7).
__global__ __launch_bounds__(NT, 4) void SR_knnModel_kernel(
    const float* __restrict__ logit,        // [B,S,V]
    const int*   __restrict__ optor_vals,   // [B,S,K]
    const float* __restrict__ optor_dists,  // [B,S,K]
    const int*   __restrict__ const_vals,   // [B,S,K]
    const float* __restrict__ const_dists,  // [B,S,K]
    const int*   __restrict__ prev_words,   // [B,S]
    const float* __restrict__ optor_lamda,  // [1]
    const float* __restrict__ const_lamda,  // [1]
    const float* __restrict__ optor_temp,   // [1]
    const float* __restrict__ const_temp,   // [1]
    float* __restrict__ out)                // [B,S,V]
{
    const int t    = threadIdx.x;
    const int wave = t >> 6;
    const int row0 = blockIdx.x * RPB;

    __shared__ float red[2][NW];

    const float ol = optor_lamda[0];
    const float cl = const_lamda[0];

    vfloat4 A[IT], B[IT];     // exp'd row buffers (double-buffered)
    float lsum = 0.f;

    // ---- prologue: row0 -> A (compiler loads; exp as they land) ----
    {
        const vfloat4* __restrict__ xin =
            (const vfloat4*)(logit + (size_t)row0 * Vc);
#pragma unroll
        for (int i = 0; i < IT; ++i) {
            const int idx = t + i * NT;
            if (i < IT - 1 || idx < V4) {
                vfloat4 v = xin[idx];
                v.x = __expf(v.x); v.y = __expf(v.y);
                v.z = __expf(v.z); v.w = __expf(v.w);
                A[i] = v;
                lsum += (v.x + v.y) + (v.z + v.w);
            }
        }
    }

    auto stage = [&](vfloat4 (&cur)[IT], vfloat4 (&nxt)[IT], const int j,
                     const bool has_next) {
        const int row = row0 + j;

        // ---- 1. asm-issue next-row loads into dedicated regs n[] ----
        vfloat4 n[IT];
        if (has_next) {
            const vfloat4* xin = (const vfloat4*)(logit + (size_t)(row + 1) * Vc);
#pragma unroll
            for (int i = 0; i < IT; ++i) {
                int idx = t + i * NT;
                if (i == IT - 1) idx = (idx < V4) ? idx : (V4 - 1); // in-bounds clamp
                asm volatile("global_load_dwordx4 %0, %1, off"
                             : "=&v"(n[i]) : "v"(xin + idx) : "memory");
            }
        }

        // ---- 2. block sum reduction; raw lgkm-only barrier (loads fly on) ----
        float s = lsum;
#pragma unroll
        for (int off = 32; off > 0; off >>= 1)
            s += __shfl_xor(s, off);
        if ((t & 63) == 0) red[j & 1][wave] = s;
        asm volatile("s_waitcnt lgkmcnt(0)\n\ts_barrier" ::: "memory");
        __builtin_amdgcn_sched_barrier(0);
        float S = 0.f;
#pragma unroll
        for (int w = 0; w < NW; ++w) S += red[j & 1][w];

        // ---- 3. per-row scalars ----
        const int pw = prev_words[row];
        const bool om_ = (pw <= 88) || (pw >= 91 && pw <= 291);
        const bool cm_ = (pw == 89) || (pw == 90) || (pw >= 292);
        const float cn = (1.f - ol) * (om_ ? 1.f : 0.f)
                       + (1.f - cl) * (cm_ ? 1.f : 0.f);
        const float f = cn / S;             // out = exp(v) * cn / S

        // ---- 4. store cur (nt); pinned between the volatile asms ----
        float* __restrict__ orow = out + (size_t)row * Vc;
#pragma unroll
        for (int i = 0; i < IT; ++i) {
            const int idx = t + i * NT;
            if (i < IT - 1 || idx < V4) {
                vfloat4 o = cur[i];
                o.x *= f; o.y *= f; o.z *= f; o.w *= f;
                __builtin_nontemporal_store(o, (vfloat4*)orow + idx);
            }
        }

        // ---- 5. counted wait: loads done, stores keep flying ----
        if (has_next) {
            if (wave < 13) asm volatile("s_waitcnt vmcnt(8)" ::: "memory");
            else           asm volatile("s_waitcnt vmcnt(7)" ::: "memory");
            __builtin_amdgcn_sched_barrier(0);
#pragma unroll
            for (int i = 0; i < IT; ++i)
                asm volatile("" : "+v"(n[i]));  // exp must read post-wait values

            // ---- 6. exp n -> nxt; next row's lsum ----
            lsum = 0.f;
#pragma unroll
            for (int i = 0; i < IT; ++i) {
                const int idx = t + i * NT;
                vfloat4 v = n[i];
                v.x = __expf(v.x); v.y = __expf(v.y);
                v.z = __expf(v.z); v.w = __expf(v.w);
                nxt[i] = v;
                if (i < IT - 1 || idx < V4)
                    lsum += (v.x + v.y) + (v.z + v.w);
            }
        }
    };

    stage(A, B, 0, true);
    stage(B, A, 1, true);
    stage(A, B, 2, true);
    stage(B, A, 3, false);

    __syncthreads();   // full vmcnt drain: all stores visible before atomics

    // ---- kNN scatter: wave w (< 4) handles row row0+w (verified R6/R7) ----
    if (wave < RPB) {
        const int row  = row0 + wave;
        const int lane = t & 63;
        const bool is_opt = lane < 32;
        const int k = lane & 31;
        const int pw = prev_words[row];
        const bool om_ = (pw <= 88) || (pw >= 91 && pw <= 291);
        const bool cm_ = (pw == 89) || (pw == 90) || (pw >= 292);
        const float scale = is_opt ? ol * (om_ ? 1.f : 0.f)
                                   : cl * (cm_ ? 1.f : 0.f);
        if (scale != 0.f) {                 // uniform within each 32-lane half
            const int*   vals  = is_opt ? optor_vals  : const_vals;
            const float* dists = is_opt ? optor_dists : const_dists;
            const float  temp  = is_opt ? optor_temp[0] : const_temp[0];
            const float sc = -dists[row * Kc + k] / temp;
            float mm = sc;
#pragma unroll
            for (int off = 16; off > 0; off >>= 1)
                mm = fmaxf(mm, __shfl_xor(mm, off));
            const float e = __expf(sc - mm);
            float sm = e;
#pragma unroll
            for (int off = 16; off > 0; off >>= 1)
                sm += __shfl_xor(sm, off);
            atomicAdd(out + (size_t)row * Vc + vals[row * Kc + k],
                      scale * (e / sm));
        }
    }
}

extern "C" void kernel_launch(void* const* d_in, const int* in_sizes, int n_in,
                              void* d_out, int out_size, void* d_ws, size_t ws_size,
                              hipStream_t stream) {
    const float* logit       = (const float*)d_in[0];
    const int*   optor_vals  = (const int*)  d_in[1];
    const float* optor_dists = (const float*)d_in[2];
    const int*   const_vals  = (const int*)  d_in[3];
    const float* const_dists = (const float*)d_in[4];
    const int*   prev_words  = (const int*)  d_in[5];
    const float* optor_lamda = (const float*)d_in[6];
    const float* const_lamda = (const float*)d_in[7];
    const float* optor_temp  = (const float*)d_in[8];
    const float* const_temp  = (const float*)d_in[9];
    float* out = (float*)d_out;

    SR_knnModel_kernel<<<GRID, NT, 0, stream>>>(
        logit, optor_vals, optor_dists, const_vals, const_dists, prev_words,
        optor_lamda, const_lamda, optor_temp, const_temp, out);
}